// Round 9
// baseline (125.907 us; speedup 1.0000x reference)
//
#include <hip/hip_runtime.h>
#include <math.h>

// ---------------- problem constants ----------------
#define NBLOCKS 4096              // one block per (b, i, pos-half-row)
#define THREADS 256               // 4 waves; wave owns 2x32-pos tiles, ALL 128 chs
#define POS_PER_BLOCK 256

typedef __attribute__((ext_vector_type(8)))  short  short8;   // MFMA A/B frag
typedef __attribute__((ext_vector_type(4)))  float  float4v;
typedef __attribute__((ext_vector_type(4)))  unsigned uint4v;
typedef __attribute__((ext_vector_type(16))) float  float16;  // 32x32 C/D frag

// gfx950 packed f32x2 -> bf16x2 (RNE), single VALU instruction
__device__ __forceinline__ unsigned cvt_pk(float lo, float hi) {
    unsigned r;
    asm("v_cvt_pk_bf16_f32 %0, %1, %2" : "=v"(r) : "v"(lo), "v"(hi));
    return r;
}

// NOTE (R1/R2): v_pk_max_i16-as-relu produced NaN twice. Do NOT reintroduce.
// NOTE (R6): exceeding the unified VGPR+AGPR residency cap costs a block.
// R9 rationale: R4-R8 show 60-67us regardless of VALU count / occupancy /
// gang size / ILP -> the per-iter __syncthreads convergence is the wall.
// Derivation: the ash h1-exchange is a LANE-WISE IDENTITY (consumer lane
// reads chunk 2ks+lh at its own l31 = the pk0/pk1 regs the same lane
// produces for ch-tile ks>>1, octet ks&1). So a wave computing layer-1 for
// ALL 128 chs of its own positions already holds layer-2's B-frags in
// registers -> delete the exchange AND every main-loop barrier. W2 A-frags
// move to LDS (staged once per block), read per use.
__device__ __forceinline__ int kmap(int c, int jj) {
    return 32 * (c >> 2) + 16 * ((c >> 1) & 1) + 4 * (c & 1) + ((jj >> 2) << 3) + (jj & 3);
}

__global__ __launch_bounds__(256, 3)
void crpb_mfma8(const float* __restrict__ gq,   // (512,3)
                const float* __restrict__ gkv,  // (4,512,3)
                const float* __restrict__ W1,   // (3,128)
                const float* __restrict__ b1,   // (128,)
                const float* __restrict__ W2,   // (128,128)
                const float* __restrict__ b2,   // (128,)
                const float* __restrict__ W3,   // (128,4)
                const float* __restrict__ b3,   // (4,)
                float* __restrict__ out)        // (16,512,512)
{
    // W2^T A-frags, frag layout: [(et*8+ks)*64 + lane] -> 4 words. 32 KB.
    __shared__ __align__(16) unsigned w2l[2048][4];
    // W3 A-frags: [(et*2+m2)*64 + lane] -> 4 words. 8 KB.
    __shared__ __align__(16) unsigned w3l[512][4];
    // feature table for this block's 256 positions (B-frag word layout)
    __shared__ __align__(16) unsigned fA[256][4];              // 4 KB
    __shared__ __align__(16) unsigned fB[256];                 // 1 KB
    __shared__ __align__(16) float b2s[128];                   // 0.5 KB

    const int tid  = threadIdx.x;
    const int lane = tid & 63;
    const int w    = __builtin_amdgcn_readfirstlane(tid >> 6);  // 0..3
    const int l31  = lane & 31;
    const int lh   = lane >> 5;

    if (tid < 128) b2s[tid] = b2[tid];

    // persistent zero C-operand (layer-1 MFMAs and first layer-3 MFMA)
    float16 z16;
    #pragma unroll
    for (int r = 0; r < 16; ++r) z16[r] = 0.0f;

    // ---- layer-1 A-frags for ALL 4 ch-tiles (W1 hi/lo + b1 folded; 16 VGPRs) ----
    short8 w1f[4];
    #pragma unroll
    for (int et = 0; et < 4; ++et) {
        const int ch = et * 32 + l31;
        const float w0 = W1[ch], w1v = W1[128 + ch], w2v = W1[256 + ch], b1v = b1[ch];
        const float w0h = __uint_as_float(cvt_pk(w0, w0) << 16);
        const float w1h = __uint_as_float(cvt_pk(w1v, w1v) << 16);
        const float w2h = __uint_as_float(cvt_pk(w2v, w2v) << 16);
        const float b1h = __uint_as_float(cvt_pk(b1v, b1v) << 16);
        const float w0l = w0 - w0h, w1l = w1v - w1h, w2l_ = w2v - w2h, b1l = b1v - b1h;
        unsigned d[4];
        if (lh == 0) {
            d[0] = cvt_pk(w0h, w0l);
            d[1] = cvt_pk(w0h, w1h);
            d[2] = cvt_pk(w1l, w1h);
            d[3] = cvt_pk(w2h, w2l_);
        } else {
            d[0] = cvt_pk(w2h, b1h);
            d[1] = cvt_pk(b1l, 0.0f);
            d[2] = 0; d[3] = 0;
        }
        __builtin_memcpy(&w1f[et], d, 16);
    }

    // ---- stage W2^T A-frags into LDS: 2048 slots, 8 per thread ----
    for (int s = tid; s < 2048; s += THREADS) {
        const int ln   = s & 63;
        const int ks   = (s >> 6) & 7;
        const int et   = s >> 9;
        const int lh_t = ln >> 5;
        const int e    = et * 32 + (ln & 31);
        const int c    = 2 * ks + lh_t;
        #pragma unroll
        for (int t = 0; t < 4; ++t) {
            const int d0 = kmap(c, 2 * t);
            w2l[s][t] = cvt_pk(W2[d0 * 128 + e], W2[(d0 + 1) * 128 + e]);
        }
    }

    // ---- stage W3 A-frags into LDS: 512 slots, 2 per thread ----
    for (int s = tid; s < 512; s += THREADS) {
        const int ln   = s & 63;
        const int m2   = (s >> 6) & 1;
        const int et   = s >> 7;
        const int lh_t = ln >> 5;
        const int l31t = ln & 31;
        #pragma unroll
        for (int t = 0; t < 4; ++t) {
            const int chl = ((2 * t) & 3) + 8 * ((2 * t) >> 2) + 4 * lh_t + 16 * m2;
            const int ch0 = et * 32 + chl;
            const float lo = (l31t < 4) ? W3[ch0 * 4 + l31t] : 0.0f;
            const float hi = (l31t < 4) ? W3[(ch0 + 1) * 4 + l31t] : 0.0f;
            w3l[s][t] = cvt_pk(lo, hi);
        }
    }

    const float b3v0 = b3[0], b3v1 = b3[1], b3v2 = b3[2], b3v3 = b3[3];

    // block-constant: (b, i, pos-half)
    const int posblock = blockIdx.x * POS_PER_BLOCK;
    const int bb    = posblock >> 18;
    const int i     = (posblock >> 9) & 511;
    const int jbase = posblock & 511;           // 0 or 256
    const float q0 = gq[i * 3 + 0], q1 = gq[i * 3 + 1], q2 = gq[i * 3 + 2];
    const float* kvrow = gkv + (size_t)((bb << 9) + jbase) * 3;

    // ---- feature precompute: 256 positions, 1/thread ----
    {
        const int jj = tid;
        const float k0 = kvrow[jj * 3 + 0], k1 = kvrow[jj * 3 + 1], k2 = kvrow[jj * 3 + 2];
        const float c0 = q0 - k0, c1 = q1 - k1, c2 = q2 - k2;
        const float f0 = copysignf(__logf(1.0f + fabsf(c0)), c0);
        const float f1 = copysignf(__logf(1.0f + fabsf(c1)), c1);
        const float f2 = copysignf(__logf(1.0f + fabsf(c2)), c2);
        const unsigned u0 = cvt_pk(f0, f0), u2 = cvt_pk(f2, f2);
        const float f0h = __uint_as_float(u0 << 16);
        const float f1h = __uint_as_float(cvt_pk(f1, f1) << 16);
        const float f2h = __uint_as_float(u2 << 16);
        const float f0l = f0 - f0h, f1l = f1 - f1h, f2l = f2 - f2h;
        fA[jj][0] = u0;                    // (f0h, f0h)
        fA[jj][1] = cvt_pk(f0l, f1);       // (f0l, f1h)
        fA[jj][2] = cvt_pk(f1, f1l);       // (f1h, f1l)
        fA[jj][3] = u2;                    // (f2h, f2h)
        fB[jj]    = cvt_pk(f2l, 1.0f);     // (f2l, 1.0) ; word1 is const
    }

    __syncthreads();   // ONLY barrier: weights + features staged

    // ======== main: 2 tiles per wave, fully wave-local, no barriers ========
    #pragma unroll
    for (int t8 = 0; t8 < 2; ++t8) {
        const int tile = w * 2 + t8;
        const int jj   = tile * 32 + l31;

        // ---- layer-1 B-frag from feature table ----
        unsigned d[4];
        if (lh == 0) {
            const uint4v t = *(const uint4v*)&fA[jj][0];
            d[0] = t[0]; d[1] = t[1]; d[2] = t[2]; d[3] = t[3];
        } else {
            d[0] = fB[jj];
            d[1] = 0x00003F80u;            // (bf16 1.0, 0) <- picks up b1
            d[2] = 0; d[3] = 0;
        }
        short8 bf; __builtin_memcpy(&bf, d, 16);

        // ---- layer-1: ALL 128 chs for this wave's 32 positions ----
        // h1f[dt][m]: the lane-wise-identity B-frags for layer-2 (32 VGPRs)
        short8 h1f[4][2];
        __builtin_amdgcn_s_setprio(1);
        #pragma unroll
        for (int et = 0; et < 4; ++et) {
            float16 c1r = __builtin_amdgcn_mfma_f32_32x32x16_bf16(w1f[et], bf, z16, 0, 0, 0);
            unsigned pk0[4], pk1[4];
            #pragma unroll
            for (int t = 0; t < 4; ++t) {
                pk0[t] = cvt_pk(fmaxf(c1r[2 * t], 0.f),     fmaxf(c1r[2 * t + 1], 0.f));
                pk1[t] = cvt_pk(fmaxf(c1r[8 + 2 * t], 0.f), fmaxf(c1r[8 + 2 * t + 1], 0.f));
            }
            __builtin_memcpy(&h1f[et][0], pk0, 16);
            __builtin_memcpy(&h1f[et][1], pk1, 16);
        }

        // ---- layer-2 + layer-3: loop over 4 e-tiles, accumulate p ----
        float16 p;
        #pragma unroll
        for (int et = 0; et < 4; ++et) {
            // acc init = b2 rows for this e-tile (4x ds_read_b128)
            float16 acc;
            #pragma unroll
            for (int qr = 0; qr < 4; ++qr) {
                const float4v bv = *(const float4v*)&b2s[et * 32 + 8 * qr + 4 * lh];
                #pragma unroll
                for (int t = 0; t < 4; ++t) acc[4 * qr + t] = bv[t];
            }
            // 8 K-step MFMAs; A from LDS, B = in-register h1 frags (identity)
            #pragma unroll
            for (int ks = 0; ks < 8; ++ks) {
                const uint4v wv = *(const uint4v*)&w2l[(et * 8 + ks) * 64 + lane][0];
                short8 af; __builtin_memcpy(&af, &wv, 16);
                acc = __builtin_amdgcn_mfma_f32_32x32x16_bf16(af, h1f[ks >> 1][ks & 1], acc, 0, 0, 0);
            }
            // relu + pack
            unsigned pa0[4], pa1[4];
            #pragma unroll
            for (int t = 0; t < 4; ++t) {
                pa0[t] = cvt_pk(fmaxf(acc[2 * t], 0.f),     fmaxf(acc[2 * t + 1], 0.f));
                pa1[t] = cvt_pk(fmaxf(acc[8 + 2 * t], 0.f), fmaxf(acc[8 + 2 * t + 1], 0.f));
            }
            short8 fa0, fa1;
            __builtin_memcpy(&fa0, pa0, 16); __builtin_memcpy(&fa1, pa1, 16);
            // layer-3 partial for this e-tile, accumulated into p
            const uint4v w30 = *(const uint4v*)&w3l[(et * 2 + 0) * 64 + lane][0];
            const uint4v w31 = *(const uint4v*)&w3l[(et * 2 + 1) * 64 + lane][0];
            short8 a30, a31;
            __builtin_memcpy(&a30, &w30, 16); __builtin_memcpy(&a31, &w31, 16);
            if (et == 0) p = __builtin_amdgcn_mfma_f32_32x32x16_bf16(a30, fa0, z16, 0, 0, 0);
            else         p = __builtin_amdgcn_mfma_f32_32x32x16_bf16(a30, fa0, p,   0, 0, 0);
            p = __builtin_amdgcn_mfma_f32_32x32x16_bf16(a31, fa1, p, 0, 0, 0);
        }
        __builtin_amdgcn_s_setprio(0);

        // ---- store: p rows 0..3 (at lh==0) are the 4 outputs ----
        if (lh == 0) {
            const size_t base = ((size_t)(bb << 2) << 18) + ((size_t)i << 9) + jbase + tile * 32 + l31;
            out[base + ((size_t)0 << 18)] = p[0] + b3v0;
            out[base + ((size_t)1 << 18)] = p[1] + b3v1;
            out[base + ((size_t)2 << 18)] = p[2] + b3v2;
            out[base + ((size_t)3 << 18)] = p[3] + b3v3;
        }
    }
}

extern "C" void kernel_launch(void* const* d_in, const int* in_sizes, int n_in,
                              void* d_out, int out_size, void* d_ws, size_t ws_size,
                              hipStream_t stream) {
    const float* gq  = (const float*)d_in[0];
    const float* gkv = (const float*)d_in[1];
    const float* W1  = (const float*)d_in[2];
    const float* b1  = (const float*)d_in[3];
    const float* W2  = (const float*)d_in[4];
    const float* b2  = (const float*)d_in[5];
    const float* W3  = (const float*)d_in[6];
    const float* b3  = (const float*)d_in[7];
    float* out = (float*)d_out;

    crpb_mfma8<<<NBLOCKS, THREADS, 0, stream>>>(gq, gkv, W1, b1, W2, b2, W3, b3, out);
}